// Round 12
// baseline (303.350 us; speedup 1.0000x reference)
//
#include <hip/hip_runtime.h>

typedef unsigned int uint;
typedef unsigned short ushort_t;
typedef short bf16x8 __attribute__((ext_vector_type(8)));
typedef float f32x4 __attribute__((ext_vector_type(4)));

// ---------- bf16 helpers ----------
__device__ __forceinline__ ushort_t f2bf(float f) {
  uint u = __builtin_bit_cast(uint, f);
  u += 0x7fffu + ((u >> 16) & 1u);
  return (ushort_t)(u >> 16);
}
__device__ __forceinline__ float bf2f(ushort_t s) {
  return __builtin_bit_cast(float, (uint)s << 16);
}
__device__ __forceinline__ bf16x8 ld_frag(const ushort_t* p) {
  return __builtin_bit_cast(bf16x8, *(const uint4*)p);
}

// ---------- Kernel 1: depthwise conv 3x3 s2 p1 + LayerNorm -> bf16 ----------
// 2x2 avg-pool FUSED (validated): pool taps == conv taps (ky,kx) in {1,2}^2.
__global__ __launch_bounds__(384) void k_convln(
    const float* __restrict__ x, const float* __restrict__ wc,
    const float* __restrict__ g, const float* __restrict__ bb,
    ushort_t* __restrict__ qout, ushort_t* __restrict__ kvout)
{
  const int b  = blockIdx.x / 784;
  const int t  = blockIdx.x % 784;
  const int oy = t / 28, ox = t % 28;
  const int c  = threadIdx.x;
  const float* xb = x + (size_t)b * 3136 * 384 + c;
  float acc = 0.f, pv = 0.f;
  #pragma unroll
  for (int ky = 0; ky < 3; ky++) {
    const int iy = 2 * oy - 1 + ky;
    const bool yok = (iy >= 0) & (iy < 56);
    #pragma unroll
    for (int kx = 0; kx < 3; kx++) {
      const int ix = 2 * ox - 1 + kx;
      if (yok & (ix >= 0) & (ix < 56)) {
        const float xv = xb[(size_t)(iy * 56 + ix) * 384];
        acc += wc[c * 9 + ky * 3 + kx] * xv;
        if ((ky >= 1) & (kx >= 1)) pv += xv;   // pool taps
      }
    }
  }
  kvout[((size_t)b * 784 + t) * 384 + c] = f2bf(pv * 0.25f);
  float s = acc, s2 = acc * acc;
  #pragma unroll
  for (int off = 32; off >= 1; off >>= 1) {
    s  += __shfl_xor(s,  off);
    s2 += __shfl_xor(s2, off);
  }
  __shared__ float ps[6], ps2[6];
  if ((c & 63) == 0) { ps[c >> 6] = s; ps2[c >> 6] = s2; }
  __syncthreads();
  float S = 0.f, S2 = 0.f;
  #pragma unroll
  for (int i = 0; i < 6; i++) { S += ps[i]; S2 += ps2[i]; }
  const float mu  = S * (1.f / 384.f);
  const float var = S2 * (1.f / 384.f) - mu * mu;
  const float inv = rsqrtf(var + 1e-5f);
  qout[((size_t)b * 784 + t) * 384 + c] = f2bf((acc - mu) * inv * g[c] + bb[c]);
}

// ---------- Kernel 2: weights f32 -> bf16 ----------
__global__ __launch_bounds__(256) void k_wcvt(
    const float* __restrict__ a, const float* __restrict__ b,
    const float* __restrict__ c, const float* __restrict__ d,
    ushort_t* __restrict__ oa, ushort_t* __restrict__ ob,
    ushort_t* __restrict__ oc, ushort_t* __restrict__ od)
{
  const int i = blockIdx.x * 256 + threadIdx.x;
  if (i < 147456) {
    oa[i] = f2bf(a[i]); ob[i] = f2bf(b[i]);
    oc[i] = f2bf(c[i]); od[i] = f2bf(d[i]);
  }
}

// ---------- Kernel 3: merged Q/K/V GEMM, 3x(M=6272 N=384 K=384) -------------
// z=0 Q (row-major), z=1 K (row-major), z=2 V (transposed out). 441 blocks.
__global__ __launch_bounds__(256) void k_gemm3(
    const ushort_t* __restrict__ Xq, const ushort_t* __restrict__ Xkv,
    const ushort_t* __restrict__ Wq, const ushort_t* __restrict__ Wk,
    const ushort_t* __restrict__ Wv,
    ushort_t* __restrict__ Qo, ushort_t* __restrict__ Ko,
    ushort_t* __restrict__ Vo)
{
  __shared__ ushort_t As[128][40];
  __shared__ ushort_t Bs[128][40];
  const int z = blockIdx.z;
  const ushort_t* X = (z == 0) ? Xq : Xkv;
  const ushort_t* W = (z == 0) ? Wq : (z == 1) ? Wk : Wv;
  const int tid = threadIdx.x, w = tid >> 6, lane = tid & 63;
  const int quad = lane >> 4, r = lane & 15;
  const int m0 = blockIdx.y * 128, n0 = blockIdx.x * 128;
  const int wm = w >> 1, wn = w & 1;
  const int lr = tid >> 2, lc = (tid & 3) << 3;
  const ushort_t* xp = X + (size_t)(m0 + lr) * 384 + lc;
  const ushort_t* wp = W + (size_t)(n0 + lr) * 384 + lc;
  f32x4 acc[4][4] = {};
  for (int k0 = 0; k0 < 384; k0 += 32) {
    __syncthreads();
    *(uint4*)&As[lr][lc]      = *(const uint4*)(xp + k0);
    *(uint4*)&As[lr + 64][lc] = *(const uint4*)(xp + (size_t)64 * 384 + k0);
    *(uint4*)&Bs[lr][lc]      = *(const uint4*)(wp + k0);
    *(uint4*)&Bs[lr + 64][lc] = *(const uint4*)(wp + (size_t)64 * 384 + k0);
    __syncthreads();
    bf16x8 af[4], bf_[4];
    #pragma unroll
    for (int mt = 0; mt < 4; mt++) af[mt]  = *(const bf16x8*)&As[wm * 64 + mt * 16 + r][quad * 8];
    #pragma unroll
    for (int nt = 0; nt < 4; nt++) bf_[nt] = *(const bf16x8*)&Bs[wn * 64 + nt * 16 + r][quad * 8];
    #pragma unroll
    for (int mt = 0; mt < 4; mt++)
      #pragma unroll
      for (int nt = 0; nt < 4; nt++)
        acc[mt][nt] = __builtin_amdgcn_mfma_f32_16x16x32_bf16(af[mt], bf_[nt], acc[mt][nt], 0, 0, 0);
  }
  #pragma unroll
  for (int mt = 0; mt < 4; mt++) {
    #pragma unroll
    for (int nt = 0; nt < 4; nt++) {
      #pragma unroll
      for (int i = 0; i < 4; i++) {
        const int row = m0 + wm * 64 + mt * 16 + quad * 4 + i;
        const int col = n0 + wn * 64 + nt * 16 + r;
        const float v = acc[mt][nt][i];
        if (z < 2) {
          ushort_t* Y = (z == 0) ? Qo : Ko;
          Y[(size_t)row * 384 + col] = f2bf(v);
        } else {
          const int bb = row / 784, tt = row % 784;
          Vo[((size_t)bb * 384 + col) * 784 + tt] = f2bf(v);
        }
      }
    }
  }
}

// ---------- Kernel 4: out-projection GEMM (M=6272 N=384 K=384, f32+bias) ----
__global__ __launch_bounds__(256) void k_gemmo(
    const ushort_t* __restrict__ X, const ushort_t* __restrict__ W,
    const float* __restrict__ bias, float* __restrict__ Y)
{
  __shared__ ushort_t As[128][40];
  __shared__ ushort_t Bs[128][40];
  const int tid = threadIdx.x, w = tid >> 6, lane = tid & 63;
  const int quad = lane >> 4, r = lane & 15;
  const int m0 = blockIdx.y * 128, n0 = blockIdx.x * 128;
  const int wm = w >> 1, wn = w & 1;
  const int lr = tid >> 2, lc = (tid & 3) << 3;
  const ushort_t* xp = X + (size_t)(m0 + lr) * 384 + lc;
  const ushort_t* wp = W + (size_t)(n0 + lr) * 384 + lc;
  f32x4 acc[4][4] = {};
  for (int k0 = 0; k0 < 384; k0 += 32) {
    __syncthreads();
    *(uint4*)&As[lr][lc]      = *(const uint4*)(xp + k0);
    *(uint4*)&As[lr + 64][lc] = *(const uint4*)(xp + (size_t)64 * 384 + k0);
    *(uint4*)&Bs[lr][lc]      = *(const uint4*)(wp + k0);
    *(uint4*)&Bs[lr + 64][lc] = *(const uint4*)(wp + (size_t)64 * 384 + k0);
    __syncthreads();
    bf16x8 af[4], bf_[4];
    #pragma unroll
    for (int mt = 0; mt < 4; mt++) af[mt]  = *(const bf16x8*)&As[wm * 64 + mt * 16 + r][quad * 8];
    #pragma unroll
    for (int nt = 0; nt < 4; nt++) bf_[nt] = *(const bf16x8*)&Bs[wn * 64 + nt * 16 + r][quad * 8];
    #pragma unroll
    for (int mt = 0; mt < 4; mt++)
      #pragma unroll
      for (int nt = 0; nt < 4; nt++)
        acc[mt][nt] = __builtin_amdgcn_mfma_f32_16x16x32_bf16(af[mt], bf_[nt], acc[mt][nt], 0, 0, 0);
  }
  #pragma unroll
  for (int mt = 0; mt < 4; mt++) {
    #pragma unroll
    for (int nt = 0; nt < 4; nt++) {
      #pragma unroll
      for (int i = 0; i < 4; i++) {
        const int row = m0 + wm * 64 + mt * 16 + quad * 4 + i;
        const int col = n0 + wn * 64 + nt * 16 + r;
        Y[(size_t)row * 384 + col] = acc[mt][nt][i] + bias[col];
      }
    }
  }
}

// ---------- Kernel 5: QK^T batched MFMA (48 batches, M=N=784, K=64) ----------
// Raw scores (scale folded into k_fusex's wf). S layout: (b, l, c, t) bf16.
__global__ __launch_bounds__(256) void k_qk(
    const ushort_t* __restrict__ Qb, const ushort_t* __restrict__ Kb,
    ushort_t* __restrict__ S)
{
  const int tid = threadIdx.x, w = tid >> 6, lane = tid & 63;
  const int quad = lane >> 4, r = lane & 15;
  const int bh = blockIdx.z, b = bh / 6, h = bh % 6;
  const int m0 = blockIdx.y * 64 + w * 16;
  const int t0 = blockIdx.x * 112;
  const int lq = min(m0 + r, 783);
  const ushort_t* qp = Qb + (size_t)(b * 784 + lq) * 384 + h * 64 + quad * 8;
  const bf16x8 a0 = ld_frag(qp), a1 = ld_frag(qp + 32);
  f32x4 acc[7] = {};
  #pragma unroll
  for (int j = 0; j < 7; j++) {
    const int t = t0 + j * 16 + r;
    const ushort_t* kp = Kb + (size_t)(b * 784 + t) * 384 + h * 64 + quad * 8;
    acc[j] = __builtin_amdgcn_mfma_f32_16x16x32_bf16(a0, ld_frag(kp),      acc[j], 0, 0, 0);
    acc[j] = __builtin_amdgcn_mfma_f32_16x16x32_bf16(a1, ld_frag(kp + 32), acc[j], 0, 0, 0);
  }
  #pragma unroll
  for (int j = 0; j < 7; j++) {
    #pragma unroll
    for (int i = 0; i < 4; i++) {
      const int lo = m0 + quad * 4 + i;
      if (lo < 784)
        S[((size_t)(b * 784 + lo) * 6 + h) * 784 + t0 + j * 16 + r] = f2bf(acc[j][i]);
    }
  }
}

// ---------- Kernel 6: fuse heads + bilinear + exp -> unnormalized P ---------
// Vectorized memory path (r11). NEW (r12): XCD-affine block swizzle (T1) —
// grid 6272 = 8 batches x 784; bl = (bid&7)*784 + bid>>3 puts each batch on
// ONE XCD under round-robin dispatch, so res_attn[b] (3.69 MB) stays resident
// in that XCD's 4 MB L2 across all 784 blocks. r11 counters: FETCH 140 MB vs
// ~88 compulsory -> ~50 MB was cross-XCD res re-fetch at ~900cy/miss; this is
// the latency the (latency-bound, 47%-of-BW) kernel pays. Bijective remap,
// correctness-neutral. Normalization deferred to k_pvs (validated).
__global__ __launch_bounds__(256) void k_fusex(
    ushort_t* __restrict__ S, const float* __restrict__ ra,
    const float* __restrict__ w_fuse, const float* __restrict__ b_fuse)
{
  const int tid = threadIdx.x;
  const int bid = blockIdx.x;
  const int bl = (bid & 7) * 784 + (bid >> 3);   // XCD j <- batch j
  const int b = bl / 784, l = bl % 784;
  __shared__ float wf[72], bfu[6];
  if (tid < 72) wf[tid] = w_fuse[tid] * ((tid % 12) < 6 ? 0.05103103630798288f : 1.f);
  if (tid < 6)  bfu[tid] = b_fuse[tid];
  __syncthreads();
  if (tid >= 196) return;

  const int Y = l / 28, X = l % 28;
  const float cy = fminf(fmaxf((float)Y * 0.5f - 0.25f, 0.f), 13.f);
  const float cx = fminf(fmaxf((float)X * 0.5f - 0.25f, 0.f), 13.f);
  const int y0 = (int)cy, y1 = min(y0 + 1, 13);
  const int x0 = (int)cx, x1 = min(x0 + 1, 13);
  const float fy = cy - (float)y0, fx = cx - (float)x0;
  const float w00 = (1.f - fy) * (1.f - fx), w01 = (1.f - fy) * fx;
  const float w10 = fy * (1.f - fx),         w11 = fy * fx;
  const int p00 = (y0 * 14 + x0) * 784, p01 = (y0 * 14 + x1) * 784;
  const int p10 = (y1 * 14 + x0) * 784, p11 = (y1 * 14 + x1) * 784;

  const int t = tid * 4;
  ushort_t* Srow = S + (size_t)bl * 6 * 784;
  const float* rab = ra + (size_t)b * 6 * 196 * 784;

  float a[6][4];
  #pragma unroll
  for (int o = 0; o < 6; o++)
    #pragma unroll
    for (int e = 0; e < 4; e++) a[o][e] = bfu[o];

  #pragma unroll
  for (int c = 0; c < 6; c++) {
    const float* rc = rab + (size_t)c * (196 * 784);
    const f32x4 r00 = *(const f32x4*)(rc + p00 + t);
    const f32x4 r01 = *(const f32x4*)(rc + p01 + t);
    const f32x4 r10 = *(const f32x4*)(rc + p10 + t);
    const f32x4 r11 = *(const f32x4*)(rc + p11 + t);
    const f32x4 rx = w00 * r00 + w01 * r01 + w10 * r10 + w11 * r11;
    const uint2 sv2 = *(const uint2*)(Srow + c * 784 + t);
    float sv[4];
    sv[0] = bf2f((ushort_t)(sv2.x & 0xffff));
    sv[1] = bf2f((ushort_t)(sv2.x >> 16));
    sv[2] = bf2f((ushort_t)(sv2.y & 0xffff));
    sv[3] = bf2f((ushort_t)(sv2.y >> 16));
    #pragma unroll
    for (int o = 0; o < 6; o++) {
      const float w1 = wf[o * 12 + c], w2 = wf[o * 12 + 6 + c];
      #pragma unroll
      for (int e = 0; e < 4; e++) a[o][e] += w1 * sv[e] + w2 * rx[e];
    }
  }
  #pragma unroll
  for (int o = 0; o < 6; o++) {
    ushort_t pk[4];
    #pragma unroll
    for (int e = 0; e < 4; e++)
      pk[e] = f2bf(__expf(fminf(a[o][e], 60.f)));   // unnormalized
    uint2 w2;
    w2.x = (uint)pk[0] | ((uint)pk[1] << 16);
    w2.y = (uint)pk[2] | ((uint)pk[3] << 16);
    *(uint2*)(Srow + o * 784 + t) = w2;
  }
}

// ---------- Kernel 7: PV batched MFMA + row-sum normalize -------------------
// Validated: A = unnormalized-exp P, full K=784 per row -> row-sum free from
// the same fragments; divide at end.
__global__ __launch_bounds__(256) void k_pvs(
    const ushort_t* __restrict__ P, const ushort_t* __restrict__ Vt,
    ushort_t* __restrict__ O)
{
  const int tid = threadIdx.x, w = tid >> 6, lane = tid & 63;
  const int quad = lane >> 4, r = lane & 15;
  const int bo = blockIdx.y, b = bo / 6, o = bo % 6;
  const int m0 = blockIdx.x * 64 + w * 16;
  const int lq = min(m0 + r, 783);
  const ushort_t* ap = P + ((size_t)(b * 784 + lq) * 6 + o) * 784 + quad * 8;
  const ushort_t* bp = Vt + ((size_t)b * 384 + o * 64 + r) * 784 + quad * 8;
  f32x4 acc[4] = {};
  float ps = 0.f;
  for (int kk = 0; kk < 25; kk++) {
    const int k0 = kk * 32;
    const bool full = (kk < 24) | (quad < 2);  // tail: K rem 16, quads 2,3 -> 0
    bf16x8 af = {}, bf_[4] = {};
    if (full) {
      af = ld_frag(ap + k0);
      const ushort_t* sv = (const ushort_t*)&af;
      #pragma unroll
      for (int e = 0; e < 8; e++) ps += bf2f(sv[e]);
      #pragma unroll
      for (int nt = 0; nt < 4; nt++) bf_[nt] = ld_frag(bp + (size_t)nt * 16 * 784 + k0);
    }
    #pragma unroll
    for (int nt = 0; nt < 4; nt++)
      acc[nt] = __builtin_amdgcn_mfma_f32_16x16x32_bf16(af, bf_[nt], acc[nt], 0, 0, 0);
  }
  ps += __shfl_xor(ps, 16);   // sum quads -> full row sum for row (m0 + r)
  ps += __shfl_xor(ps, 32);
  float inv[4];
  #pragma unroll
  for (int i = 0; i < 4; i++) inv[i] = 1.f / __shfl(ps, quad * 4 + i);
  #pragma unroll
  for (int nt = 0; nt < 4; nt++) {
    #pragma unroll
    for (int i = 0; i < 4; i++) {
      const int lo = m0 + quad * 4 + i;
      if (lo < 784)
        O[(size_t)(b * 784 + lo) * 384 + o * 64 + nt * 16 + r] =
            f2bf(acc[nt][i] * inv[i]);
    }
  }
}

// ---------- host launcher ----------
extern "C" void kernel_launch(void* const* d_in, const int* in_sizes, int n_in,
                              void* d_out, int out_size, void* d_ws, size_t ws_size,
                              hipStream_t stream)
{
  const float* x        = (const float*)d_in[0];
  const float* res_attn = (const float*)d_in[1];
  const float* conv_w   = (const float*)d_in[2];
  const float* ln_g     = (const float*)d_in[3];
  const float* ln_b     = (const float*)d_in[4];
  const float* wq       = (const float*)d_in[5];
  const float* wk       = (const float*)d_in[6];
  const float* wv       = (const float*)d_in[7];
  const float* w_proj   = (const float*)d_in[8];
  const float* b_proj   = (const float*)d_in[9];
  const float* w_fuse   = (const float*)d_in[10];
  const float* b_fuse   = (const float*)d_in[11];
  float* out = (float*)d_out;

  // ws layout (bf16 elements), ~89 MB — proven layout (S -> P in place)
  const size_t NE = (size_t)8 * 784 * 384;      // 2,408,448
  const size_t NW = 147456;
  ushort_t* q_ln_b = (ushort_t*)d_ws;
  ushort_t* kv_b   = q_ln_b + NE;
  ushort_t* Qb     = kv_b + NE;
  ushort_t* Kb     = Qb + NE;
  ushort_t* Vt     = Kb + NE;   // (b, 384, 784)
  ushort_t* Opre   = Vt + NE;
  ushort_t* wqb    = Opre + NE;
  ushort_t* wkb    = wqb + NW;
  ushort_t* wvb    = wkb + NW;
  ushort_t* wpb    = wvb + NW;
  ushort_t* S      = wpb + NW;  // (b, 784, 6, 784) scores -> unnorm P in place

  k_convln<<<dim3(8 * 784), dim3(384), 0, stream>>>(x, conv_w, ln_g, ln_b, q_ln_b, kv_b);
  k_wcvt  <<<dim3(576),     dim3(256), 0, stream>>>(wq, wk, wv, w_proj, wqb, wkb, wvb, wpb);

  k_gemm3<<<dim3(3, 49, 3), dim3(256), 0, stream>>>(
      q_ln_b, kv_b, wqb, wkb, wvb, Qb, Kb, Vt);

  k_qk   <<<dim3(7, 13, 48), dim3(256), 0, stream>>>(Qb, Kb, S);
  k_fusex<<<dim3(8 * 784),   dim3(256), 0, stream>>>(S, res_attn, w_fuse, b_fuse);
  k_pvs  <<<dim3(13, 48),    dim3(256), 0, stream>>>(S, Vt, Opre);

  k_gemmo<<<dim3(3, 49), dim3(256), 0, stream>>>(Opre, wpb, b_proj, out);
}

// Round 13
// 300.003 us; speedup vs baseline: 1.0112x; 1.0112x over previous
//
#include <hip/hip_runtime.h>

typedef unsigned int uint;
typedef unsigned short ushort_t;
typedef short bf16x8 __attribute__((ext_vector_type(8)));
typedef float f32x4 __attribute__((ext_vector_type(4)));

// ---------- bf16 helpers ----------
__device__ __forceinline__ ushort_t f2bf(float f) {
  uint u = __builtin_bit_cast(uint, f);
  u += 0x7fffu + ((u >> 16) & 1u);
  return (ushort_t)(u >> 16);
}
__device__ __forceinline__ float bf2f(ushort_t s) {
  return __builtin_bit_cast(float, (uint)s << 16);
}
__device__ __forceinline__ bf16x8 ld_frag(const ushort_t* p) {
  return __builtin_bit_cast(bf16x8, *(const uint4*)p);
}

// ---------- Kernel 1: depthwise conv 3x3 s2 p1 + LayerNorm -> bf16 ----------
// 2x2 avg-pool FUSED (validated): pool taps == conv taps (ky,kx) in {1,2}^2.
__global__ __launch_bounds__(384) void k_convln(
    const float* __restrict__ x, const float* __restrict__ wc,
    const float* __restrict__ g, const float* __restrict__ bb,
    ushort_t* __restrict__ qout, ushort_t* __restrict__ kvout)
{
  const int b  = blockIdx.x / 784;
  const int t  = blockIdx.x % 784;
  const int oy = t / 28, ox = t % 28;
  const int c  = threadIdx.x;
  const float* xb = x + (size_t)b * 3136 * 384 + c;
  float acc = 0.f, pv = 0.f;
  #pragma unroll
  for (int ky = 0; ky < 3; ky++) {
    const int iy = 2 * oy - 1 + ky;
    const bool yok = (iy >= 0) & (iy < 56);
    #pragma unroll
    for (int kx = 0; kx < 3; kx++) {
      const int ix = 2 * ox - 1 + kx;
      if (yok & (ix >= 0) & (ix < 56)) {
        const float xv = xb[(size_t)(iy * 56 + ix) * 384];
        acc += wc[c * 9 + ky * 3 + kx] * xv;
        if ((ky >= 1) & (kx >= 1)) pv += xv;   // pool taps
      }
    }
  }
  kvout[((size_t)b * 784 + t) * 384 + c] = f2bf(pv * 0.25f);
  float s = acc, s2 = acc * acc;
  #pragma unroll
  for (int off = 32; off >= 1; off >>= 1) {
    s  += __shfl_xor(s,  off);
    s2 += __shfl_xor(s2, off);
  }
  __shared__ float ps[6], ps2[6];
  if ((c & 63) == 0) { ps[c >> 6] = s; ps2[c >> 6] = s2; }
  __syncthreads();
  float S = 0.f, S2 = 0.f;
  #pragma unroll
  for (int i = 0; i < 6; i++) { S += ps[i]; S2 += ps2[i]; }
  const float mu  = S * (1.f / 384.f);
  const float var = S2 * (1.f / 384.f) - mu * mu;
  const float inv = rsqrtf(var + 1e-5f);
  qout[((size_t)b * 784 + t) * 384 + c] = f2bf((acc - mu) * inv * g[c] + bb[c]);
}

// ---------- Kernel 2: weights f32 -> bf16 ----------
__global__ __launch_bounds__(256) void k_wcvt(
    const float* __restrict__ a, const float* __restrict__ b,
    const float* __restrict__ c, const float* __restrict__ d,
    ushort_t* __restrict__ oa, ushort_t* __restrict__ ob,
    ushort_t* __restrict__ oc, ushort_t* __restrict__ od)
{
  const int i = blockIdx.x * 256 + threadIdx.x;
  if (i < 147456) {
    oa[i] = f2bf(a[i]); ob[i] = f2bf(b[i]);
    oc[i] = f2bf(c[i]); od[i] = f2bf(d[i]);
  }
}

// ---------- Kernel 3: merged Q/K/V GEMM, 3x(M=6272 N=384 K=384) -------------
// z=0 Q (row-major), z=1 K (row-major), z=2 V (transposed out). 441 blocks.
__global__ __launch_bounds__(256) void k_gemm3(
    const ushort_t* __restrict__ Xq, const ushort_t* __restrict__ Xkv,
    const ushort_t* __restrict__ Wq, const ushort_t* __restrict__ Wk,
    const ushort_t* __restrict__ Wv,
    ushort_t* __restrict__ Qo, ushort_t* __restrict__ Ko,
    ushort_t* __restrict__ Vo)
{
  __shared__ ushort_t As[128][40];
  __shared__ ushort_t Bs[128][40];
  const int z = blockIdx.z;
  const ushort_t* X = (z == 0) ? Xq : Xkv;
  const ushort_t* W = (z == 0) ? Wq : (z == 1) ? Wk : Wv;
  const int tid = threadIdx.x, w = tid >> 6, lane = tid & 63;
  const int quad = lane >> 4, r = lane & 15;
  const int m0 = blockIdx.y * 128, n0 = blockIdx.x * 128;
  const int wm = w >> 1, wn = w & 1;
  const int lr = tid >> 2, lc = (tid & 3) << 3;
  const ushort_t* xp = X + (size_t)(m0 + lr) * 384 + lc;
  const ushort_t* wp = W + (size_t)(n0 + lr) * 384 + lc;
  f32x4 acc[4][4] = {};
  for (int k0 = 0; k0 < 384; k0 += 32) {
    __syncthreads();
    *(uint4*)&As[lr][lc]      = *(const uint4*)(xp + k0);
    *(uint4*)&As[lr + 64][lc] = *(const uint4*)(xp + (size_t)64 * 384 + k0);
    *(uint4*)&Bs[lr][lc]      = *(const uint4*)(wp + k0);
    *(uint4*)&Bs[lr + 64][lc] = *(const uint4*)(wp + (size_t)64 * 384 + k0);
    __syncthreads();
    bf16x8 af[4], bf_[4];
    #pragma unroll
    for (int mt = 0; mt < 4; mt++) af[mt]  = *(const bf16x8*)&As[wm * 64 + mt * 16 + r][quad * 8];
    #pragma unroll
    for (int nt = 0; nt < 4; nt++) bf_[nt] = *(const bf16x8*)&Bs[wn * 64 + nt * 16 + r][quad * 8];
    #pragma unroll
    for (int mt = 0; mt < 4; mt++)
      #pragma unroll
      for (int nt = 0; nt < 4; nt++)
        acc[mt][nt] = __builtin_amdgcn_mfma_f32_16x16x32_bf16(af[mt], bf_[nt], acc[mt][nt], 0, 0, 0);
  }
  #pragma unroll
  for (int mt = 0; mt < 4; mt++) {
    #pragma unroll
    for (int nt = 0; nt < 4; nt++) {
      #pragma unroll
      for (int i = 0; i < 4; i++) {
        const int row = m0 + wm * 64 + mt * 16 + quad * 4 + i;
        const int col = n0 + wn * 64 + nt * 16 + r;
        const float v = acc[mt][nt][i];
        if (z < 2) {
          ushort_t* Y = (z == 0) ? Qo : Ko;
          Y[(size_t)row * 384 + col] = f2bf(v);
        } else {
          const int bb = row / 784, tt = row % 784;
          Vo[((size_t)bb * 384 + col) * 784 + tt] = f2bf(v);
        }
      }
    }
  }
}

// ---------- Kernel 4: out-projection GEMM (M=6272 N=384 K=384, f32+bias) ----
__global__ __launch_bounds__(256) void k_gemmo(
    const ushort_t* __restrict__ X, const ushort_t* __restrict__ W,
    const float* __restrict__ bias, float* __restrict__ Y)
{
  __shared__ ushort_t As[128][40];
  __shared__ ushort_t Bs[128][40];
  const int tid = threadIdx.x, w = tid >> 6, lane = tid & 63;
  const int quad = lane >> 4, r = lane & 15;
  const int m0 = blockIdx.y * 128, n0 = blockIdx.x * 128;
  const int wm = w >> 1, wn = w & 1;
  const int lr = tid >> 2, lc = (tid & 3) << 3;
  const ushort_t* xp = X + (size_t)(m0 + lr) * 384 + lc;
  const ushort_t* wp = W + (size_t)(n0 + lr) * 384 + lc;
  f32x4 acc[4][4] = {};
  for (int k0 = 0; k0 < 384; k0 += 32) {
    __syncthreads();
    *(uint4*)&As[lr][lc]      = *(const uint4*)(xp + k0);
    *(uint4*)&As[lr + 64][lc] = *(const uint4*)(xp + (size_t)64 * 384 + k0);
    *(uint4*)&Bs[lr][lc]      = *(const uint4*)(wp + k0);
    *(uint4*)&Bs[lr + 64][lc] = *(const uint4*)(wp + (size_t)64 * 384 + k0);
    __syncthreads();
    bf16x8 af[4], bf_[4];
    #pragma unroll
    for (int mt = 0; mt < 4; mt++) af[mt]  = *(const bf16x8*)&As[wm * 64 + mt * 16 + r][quad * 8];
    #pragma unroll
    for (int nt = 0; nt < 4; nt++) bf_[nt] = *(const bf16x8*)&Bs[wn * 64 + nt * 16 + r][quad * 8];
    #pragma unroll
    for (int mt = 0; mt < 4; mt++)
      #pragma unroll
      for (int nt = 0; nt < 4; nt++)
        acc[mt][nt] = __builtin_amdgcn_mfma_f32_16x16x32_bf16(af[mt], bf_[nt], acc[mt][nt], 0, 0, 0);
  }
  #pragma unroll
  for (int mt = 0; mt < 4; mt++) {
    #pragma unroll
    for (int nt = 0; nt < 4; nt++) {
      #pragma unroll
      for (int i = 0; i < 4; i++) {
        const int row = m0 + wm * 64 + mt * 16 + quad * 4 + i;
        const int col = n0 + wn * 64 + nt * 16 + r;
        Y[(size_t)row * 384 + col] = acc[mt][nt][i] + bias[col];
      }
    }
  }
}

// ---------- Kernel 5: QK^T batched MFMA (48 batches, M=N=784, K=64) ----------
// Raw scores (scale folded into k_fusex's wf). S layout: (b, l, c, t) bf16.
__global__ __launch_bounds__(256) void k_qk(
    const ushort_t* __restrict__ Qb, const ushort_t* __restrict__ Kb,
    ushort_t* __restrict__ S)
{
  const int tid = threadIdx.x, w = tid >> 6, lane = tid & 63;
  const int quad = lane >> 4, r = lane & 15;
  const int bh = blockIdx.z, b = bh / 6, h = bh % 6;
  const int m0 = blockIdx.y * 64 + w * 16;
  const int t0 = blockIdx.x * 112;
  const int lq = min(m0 + r, 783);
  const ushort_t* qp = Qb + (size_t)(b * 784 + lq) * 384 + h * 64 + quad * 8;
  const bf16x8 a0 = ld_frag(qp), a1 = ld_frag(qp + 32);
  f32x4 acc[7] = {};
  #pragma unroll
  for (int j = 0; j < 7; j++) {
    const int t = t0 + j * 16 + r;
    const ushort_t* kp = Kb + (size_t)(b * 784 + t) * 384 + h * 64 + quad * 8;
    acc[j] = __builtin_amdgcn_mfma_f32_16x16x32_bf16(a0, ld_frag(kp),      acc[j], 0, 0, 0);
    acc[j] = __builtin_amdgcn_mfma_f32_16x16x32_bf16(a1, ld_frag(kp + 32), acc[j], 0, 0, 0);
  }
  #pragma unroll
  for (int j = 0; j < 7; j++) {
    #pragma unroll
    for (int i = 0; i < 4; i++) {
      const int lo = m0 + quad * 4 + i;
      if (lo < 784)
        S[((size_t)(b * 784 + lo) * 6 + h) * 784 + t0 + j * 16 + r] = f2bf(acc[j][i]);
    }
  }
}

// ---------- Kernel 6: fuse heads + bilinear + exp -> unnormalized P ---------
// r11: vectorized (uint2 S, f32x4 res). r12: XCD-affine swizzle (FETCH 140->43
// MB, kept). r13: ISSUE-EARLY/COMPUTE-LATE — r12 counters (dur flat despite
// -100MB HBM, VGPR 84 => compiler kept only one c-group of loads in flight)
// show 6 serialized ~200cy L2 latency windows per thread. Hoist ALL 24 res
// gathers + 6 S loads into statically-indexed register arrays (rule #20:
// every index compile-time) -> one latency window, ~160 VGPR, no spill.
// Normalization deferred to k_pvs (validated).
__global__ __launch_bounds__(256) void k_fusex(
    ushort_t* __restrict__ S, const float* __restrict__ ra,
    const float* __restrict__ w_fuse, const float* __restrict__ b_fuse)
{
  const int tid = threadIdx.x;
  const int bid = blockIdx.x;
  const int bl = (bid & 7) * 784 + (bid >> 3);   // XCD j <- batch j
  const int b = bl / 784, l = bl % 784;
  __shared__ float wf[72], bfu[6];
  if (tid < 72) wf[tid] = w_fuse[tid] * ((tid % 12) < 6 ? 0.05103103630798288f : 1.f);
  if (tid < 6)  bfu[tid] = b_fuse[tid];
  __syncthreads();
  if (tid >= 196) return;

  const int Y = l / 28, X = l % 28;
  const float cy = fminf(fmaxf((float)Y * 0.5f - 0.25f, 0.f), 13.f);
  const float cx = fminf(fmaxf((float)X * 0.5f - 0.25f, 0.f), 13.f);
  const int y0 = (int)cy, y1 = min(y0 + 1, 13);
  const int x0 = (int)cx, x1 = min(x0 + 1, 13);
  const float fy = cy - (float)y0, fx = cx - (float)x0;
  const float w00 = (1.f - fy) * (1.f - fx), w01 = (1.f - fy) * fx;
  const float w10 = fy * (1.f - fx),         w11 = fy * fx;
  const int p00 = (y0 * 14 + x0) * 784, p01 = (y0 * 14 + x1) * 784;
  const int p10 = (y1 * 14 + x0) * 784, p11 = (y1 * 14 + x1) * 784;

  const int t = tid * 4;
  ushort_t* Srow = S + (size_t)bl * 6 * 784;
  const float* rab = ra + (size_t)b * 6 * 196 * 784;

  // ---- phase 1: issue ALL loads (30 VMEM ops in flight) ----
  f32x4 g00[6], g01[6], g10[6], g11[6];
  uint2 sraw[6];
  #pragma unroll
  for (int c = 0; c < 6; c++) {
    const float* rc = rab + (size_t)c * (196 * 784);
    g00[c] = *(const f32x4*)(rc + p00 + t);
    g01[c] = *(const f32x4*)(rc + p01 + t);
    g10[c] = *(const f32x4*)(rc + p10 + t);
    g11[c] = *(const f32x4*)(rc + p11 + t);
    sraw[c] = *(const uint2*)(Srow + c * 784 + t);
  }

  // ---- phase 2: compute ----
  float a[6][4];
  #pragma unroll
  for (int o = 0; o < 6; o++)
    #pragma unroll
    for (int e = 0; e < 4; e++) a[o][e] = bfu[o];

  #pragma unroll
  for (int c = 0; c < 6; c++) {
    const f32x4 rx = w00 * g00[c] + w01 * g01[c] + w10 * g10[c] + w11 * g11[c];
    float sv[4];
    sv[0] = bf2f((ushort_t)(sraw[c].x & 0xffff));
    sv[1] = bf2f((ushort_t)(sraw[c].x >> 16));
    sv[2] = bf2f((ushort_t)(sraw[c].y & 0xffff));
    sv[3] = bf2f((ushort_t)(sraw[c].y >> 16));
    #pragma unroll
    for (int o = 0; o < 6; o++) {
      const float w1 = wf[o * 12 + c], w2 = wf[o * 12 + 6 + c];
      #pragma unroll
      for (int e = 0; e < 4; e++) a[o][e] += w1 * sv[e] + w2 * rx[e];
    }
  }
  #pragma unroll
  for (int o = 0; o < 6; o++) {
    ushort_t pk[4];
    #pragma unroll
    for (int e = 0; e < 4; e++)
      pk[e] = f2bf(__expf(fminf(a[o][e], 60.f)));   // unnormalized
    uint2 w2;
    w2.x = (uint)pk[0] | ((uint)pk[1] << 16);
    w2.y = (uint)pk[2] | ((uint)pk[3] << 16);
    *(uint2*)(Srow + o * 784 + t) = w2;
  }
}

// ---------- Kernel 7: PV batched MFMA + row-sum normalize -------------------
// Validated: A = unnormalized-exp P, full K=784 per row -> row-sum free from
// the same fragments; divide at end.
__global__ __launch_bounds__(256) void k_pvs(
    const ushort_t* __restrict__ P, const ushort_t* __restrict__ Vt,
    ushort_t* __restrict__ O)
{
  const int tid = threadIdx.x, w = tid >> 6, lane = tid & 63;
  const int quad = lane >> 4, r = lane & 15;
  const int bo = blockIdx.y, b = bo / 6, o = bo % 6;
  const int m0 = blockIdx.x * 64 + w * 16;
  const int lq = min(m0 + r, 783);
  const ushort_t* ap = P + ((size_t)(b * 784 + lq) * 6 + o) * 784 + quad * 8;
  const ushort_t* bp = Vt + ((size_t)b * 384 + o * 64 + r) * 784 + quad * 8;
  f32x4 acc[4] = {};
  float ps = 0.f;
  for (int kk = 0; kk < 25; kk++) {
    const int k0 = kk * 32;
    const bool full = (kk < 24) | (quad < 2);  // tail: K rem 16, quads 2,3 -> 0
    bf16x8 af = {}, bf_[4] = {};
    if (full) {
      af = ld_frag(ap + k0);
      const ushort_t* sv = (const ushort_t*)&af;
      #pragma unroll
      for (int e = 0; e < 8; e++) ps += bf2f(sv[e]);
      #pragma unroll
      for (int nt = 0; nt < 4; nt++) bf_[nt] = ld_frag(bp + (size_t)nt * 16 * 784 + k0);
    }
    #pragma unroll
    for (int nt = 0; nt < 4; nt++)
      acc[nt] = __builtin_amdgcn_mfma_f32_16x16x32_bf16(af, bf_[nt], acc[nt], 0, 0, 0);
  }
  ps += __shfl_xor(ps, 16);   // sum quads -> full row sum for row (m0 + r)
  ps += __shfl_xor(ps, 32);
  float inv[4];
  #pragma unroll
  for (int i = 0; i < 4; i++) inv[i] = 1.f / __shfl(ps, quad * 4 + i);
  #pragma unroll
  for (int nt = 0; nt < 4; nt++) {
    #pragma unroll
    for (int i = 0; i < 4; i++) {
      const int lo = m0 + quad * 4 + i;
      if (lo < 784)
        O[(size_t)(b * 784 + lo) * 384 + o * 64 + nt * 16 + r] =
            f2bf(acc[nt][i] * inv[i]);
    }
  }
}

// ---------- host launcher ----------
extern "C" void kernel_launch(void* const* d_in, const int* in_sizes, int n_in,
                              void* d_out, int out_size, void* d_ws, size_t ws_size,
                              hipStream_t stream)
{
  const float* x        = (const float*)d_in[0];
  const float* res_attn = (const float*)d_in[1];
  const float* conv_w   = (const float*)d_in[2];
  const float* ln_g     = (const float*)d_in[3];
  const float* ln_b     = (const float*)d_in[4];
  const float* wq       = (const float*)d_in[5];
  const float* wk       = (const float*)d_in[6];
  const float* wv       = (const float*)d_in[7];
  const float* w_proj   = (const float*)d_in[8];
  const float* b_proj   = (const float*)d_in[9];
  const float* w_fuse   = (const float*)d_in[10];
  const float* b_fuse   = (const float*)d_in[11];
  float* out = (float*)d_out;

  // ws layout (bf16 elements), ~89 MB — proven layout (S -> P in place)
  const size_t NE = (size_t)8 * 784 * 384;      // 2,408,448
  const size_t NW = 147456;
  ushort_t* q_ln_b = (ushort_t*)d_ws;
  ushort_t* kv_b   = q_ln_b + NE;
  ushort_t* Qb     = kv_b + NE;
  ushort_t* Kb     = Qb + NE;
  ushort_t* Vt     = Kb + NE;   // (b, 384, 784)
  ushort_t* Opre   = Vt + NE;
  ushort_t* wqb    = Opre + NE;
  ushort_t* wkb    = wqb + NW;
  ushort_t* wvb    = wkb + NW;
  ushort_t* wpb    = wvb + NW;
  ushort_t* S      = wpb + NW;  // (b, 784, 6, 784) scores -> unnorm P in place

  k_convln<<<dim3(8 * 784), dim3(384), 0, stream>>>(x, conv_w, ln_g, ln_b, q_ln_b, kv_b);
  k_wcvt  <<<dim3(576),     dim3(256), 0, stream>>>(wq, wk, wv, w_proj, wqb, wkb, wvb, wpb);

  k_gemm3<<<dim3(3, 49, 3), dim3(256), 0, stream>>>(
      q_ln_b, kv_b, wqb, wkb, wvb, Qb, Kb, Vt);

  k_qk   <<<dim3(7, 13, 48), dim3(256), 0, stream>>>(Qb, Kb, S);
  k_fusex<<<dim3(8 * 784),   dim3(256), 0, stream>>>(S, res_attn, w_fuse, b_fuse);
  k_pvs  <<<dim3(13, 48),    dim3(256), 0, stream>>>(S, Vt, Opre);

  k_gemmo<<<dim3(3, 49), dim3(256), 0, stream>>>(Opre, wpb, b_proj, out);
}